// Round 5
// baseline (883.290 us; speedup 1.0000x reference)
//
#include <hip/hip_runtime.h>
#include <math.h>

// ---------- config ----------
#define T_TOK 4096
#define DIM   2048
#define NEXP  32
#define TOPK  4
#define CAP   160          // ceil(1.25*4096/32)
#define ECAP  (NEXP*CAP)   // 5120
#define ISZ   1024         // moe intermediate
#define ISH   2048         // shared intermediate (I*NSH)

typedef short bf16x8 __attribute__((ext_vector_type(8)));
typedef float f32x4  __attribute__((ext_vector_type(4)));

__device__ __forceinline__ unsigned int f2bf(float f){
  union { float f; unsigned int u; } v; v.f = f;
  return (v.u + 0x7fffu + ((v.u >> 16) & 1u)) >> 16;   // RNE
}

// async global->LDS, 16B/lane; LDS base wave-uniform (HW adds lane*16), global addr per-lane
#define GLOAD16(g, l) __builtin_amdgcn_global_load_lds( \
    (const __attribute__((address_space(1))) unsigned int*)(g), \
    (__attribute__((address_space(3))) unsigned int*)(l), 16, 0, 0)

// ---------- fp32 -> bf16 convert (layout-preserving) ----------
__global__ __launch_bounds__(256) void cvt_k(const float* __restrict__ in,
                                             unsigned short* __restrict__ out, int n8){
  int i = blockIdx.x*256 + threadIdx.x;
  if (i >= n8) return;
  const float4 a = *(const float4*)&in[(size_t)i*8];
  const float4 b = *(const float4*)&in[(size_t)i*8 + 4];
  uint4 v;
  v.x = f2bf(a.x) | (f2bf(a.y) << 16);
  v.y = f2bf(a.z) | (f2bf(a.w) << 16);
  v.z = f2bf(b.x) | (f2bf(b.y) << 16);
  v.w = f2bf(b.z) | (f2bf(b.w) << 16);
  *(uint4*)&out[(size_t)i*8] = v;
}

// ---------- fp32 [R,C] -> bf16 [C,R] transpose-convert, per expert (blockIdx.z) ----------
// 128x128 tiles; LDS XOR-swizzle byte ^= (r&31)<<2 makes both phases ~conflict-free.
template<int R, int C>
__global__ __launch_bounds__(256) void tcvt_k(const float* __restrict__ src,
                                              unsigned short* __restrict__ dst){
  __shared__ unsigned short tile[128*128];
  const int tid = threadIdx.x;
  const size_t eoff = (size_t)blockIdx.z * R * C;
  const int tj = blockIdx.x, ti = blockIdx.y;   // col-tile, row-tile of src
  const float* s = src + eoff + (size_t)(ti*128)*C + tj*128;
  #pragma unroll
  for (int q = 0; q < 16; ++q){
    int flat = q*256 + tid;
    int r = flat >> 5, c4 = (flat & 31) << 2;
    float4 f = *(const float4*)&s[(size_t)r*C + c4];
    unsigned int w0 = f2bf(f.x) | (f2bf(f.y) << 16);
    unsigned int w1 = f2bf(f.z) | (f2bf(f.w) << 16);
    int b = r*256 + ((c4*2) ^ ((r & 31) << 2));
    *(unsigned int*)((char*)tile + b) = w0;
    *(unsigned int*)((char*)tile + (b ^ 4)) = w1;
  }
  __syncthreads();
  unsigned short* d = dst + eoff;
  #pragma unroll
  for (int q = 0; q < 32; ++q){
    int flat = q*256 + tid;
    int oc = flat >> 6;             // src col within tile
    int c2 = (flat & 63) << 1;      // src row pair
    int b0 = c2*256     + ((oc*2) ^ (( c2    & 31) << 2));
    int b1 = (c2+1)*256 + ((oc*2) ^ (((c2+1) & 31) << 2));
    unsigned int lo = *(const unsigned short*)((const char*)tile + b0);
    unsigned int hi = *(const unsigned short*)((const char*)tile + b1);
    *(unsigned int*)&d[(size_t)(tj*128 + oc)*R + ti*128 + c2] = lo | (hi << 16);
  }
}

// ---------- router: fp64 logits, exact top-k semantics ----------
__global__ __launch_bounds__(256) void router_k(const float* __restrict__ x,
                                                const float* __restrict__ rw,
                                                const float* __restrict__ eb,
                                                int* __restrict__ tki,
                                                float* __restrict__ tkw){
  __shared__ float  xs[4][DIM];
  __shared__ double ssh[4][NEXP];
  const int tb = blockIdx.x * 4;
  const int tid = threadIdx.x;
  for (int i = tid; i < 4*(DIM/4); i += 256){
    int t = i >> 9, c = (i & 511) << 2;
    *(float4*)&xs[t][c] = *(const float4*)&x[(size_t)(tb + t)*DIM + c];
  }
  __syncthreads();
  const int lane = tid & 63, wv = tid >> 6;
  for (int ei = 0; ei < 8; ++ei){
    int e = wv*8 + ei;
    double a0=0, a1=0, a2=0, a3=0;
    for (int d = lane; d < DIM; d += 64){
      double w = (double)rw[(size_t)e*DIM + d];
      a0 += (double)xs[0][d] * w;
      a1 += (double)xs[1][d] * w;
      a2 += (double)xs[2][d] * w;
      a3 += (double)xs[3][d] * w;
    }
    for (int off = 32; off; off >>= 1){
      a0 += __shfl_down(a0, off);
      a1 += __shfl_down(a1, off);
      a2 += __shfl_down(a2, off);
      a3 += __shfl_down(a3, off);
    }
    if (lane == 0){ ssh[0][e]=a0; ssh[1][e]=a1; ssh[2][e]=a2; ssh[3][e]=a3; }
  }
  __syncthreads();
  if (tid < 4){
    const int t = tid;
    double s[NEXP], sc[NEXP];
    for (int e = 0; e < NEXP; ++e){
      double sig = 1.0 / (1.0 + exp(-ssh[t][e]));
      s[e] = sig; sc[e] = sig + (double)eb[e];
    }
    double gsc[8];
    for (int g = 0; g < 8; ++g){
      double b0=sc[g*4],b1=sc[g*4+1],b2=sc[g*4+2],b3=sc[g*4+3];
      double h1=fmax(b0,b1), l1=fmin(b0,b1);
      double h2=fmax(b2,b3), l2=fmin(b2,b3);
      double top = fmax(h1,h2);
      double sec = fmax(fmin(h1,h2), (h1 >= h2) ? l1 : l2);
      gsc[g] = top + sec;
    }
    int gsel = 0;
    for (int r = 0; r < 3; ++r){
      int bi = -1; double bv = -1e300;
      for (int g = 0; g < 8; ++g)
        if (!((gsel >> g) & 1) && gsc[g] > bv){ bv = gsc[g]; bi = g; }
      gsel |= 1 << bi;
    }
    double mval[NEXP];
    for (int e = 0; e < NEXP; ++e)
      mval[e] = ((gsel >> (e >> 2)) & 1) ? sc[e] : 0.0;
    int idx4[4]; double wsum = 0.0, wv4[4];
    for (int r = 0; r < 4; ++r){
      int bi = -1; double bv = -1e300;
      for (int e = 0; e < NEXP; ++e)
        if (mval[e] > bv){ bv = mval[e]; bi = e; }
      idx4[r] = bi; mval[bi] = -1e300;
      wv4[r] = s[bi]; wsum += wv4[r];
    }
    const int gt = tb + t;
    for (int r = 0; r < 4; ++r){
      tki[gt*4 + r] = idx4[r];
      tkw[gt*4 + r] = (float)(wv4[r] / (wsum + 1e-20) * 2.5);
    }
  }
}

// ---------- dispatch: wave per expert, stable-order rank scan ----------
__global__ __launch_bounds__(1024) void dispatch_k(const int* __restrict__ tki,
                                                   const float* __restrict__ tkw,
                                                   int* __restrict__ stok,
                                                   float* __restrict__ sw){
  const int e = blockIdx.x*16 + (threadIdx.x >> 6);
  const int lane = threadIdx.x & 63;
  int base = 0;
  for (int it = 0; it < (T_TOK*TOPK)/64; ++it){
    if (base >= CAP) break;
    int idx = it*64 + lane;
    int ex = tki[idx];
    bool m = (ex == e);
    unsigned long long mk = __ballot(m);
    int pos = base + __popcll(mk & ((1ull << lane) - 1ull));
    if (m && pos < CAP){
      stok[e*CAP + pos] = idx >> 2;
      sw[e*CAP + pos]   = tkw[idx];
    }
    base += __popcll(mk);
  }
}

// ---------- MFMA GEMM: ALL-bf16, pure global_load_lds staging (m97 pattern) ----------
// A: bf16 [M,KK] (EXPERT&&GU: rows gathered via stok). B: bf16 [N,KK] (pre-converted).
// GU=1: H(bf16) = silu(A@Bg^T)*(A@Bu^T); GU=0: out(f32) = A@B^T (EXPERT: atomic scatter).
// All configs: 32 groups x 32 nblks = 1024 blocks; plane LDS (16 rows x 32k = 1KB),
// every LDS op is uniform_base + lane*16 -> conflict-free.
template<int EXPERT, int GU>
__global__ __launch_bounds__(256, 4)
void gemm5_k(const unsigned short* __restrict__ Ab,
             const unsigned short* __restrict__ B0,
             const unsigned short* __restrict__ B1,
             void* __restrict__ Co,
             const int* __restrict__ stok, const float* __restrict__ sw){
  constexpr int BM   = EXPERT ? 160 : 128;
  constexpr int APL  = BM/16;                       // A planes (10 / 8)
  constexpr int FM   = APL/2;                       // A frags per wave
  constexpr int KK   = GU ? DIM : (EXPERT ? ISZ : ISH);
  constexpr int LDC  = GU ? (EXPERT ? ISZ : ISH) : DIM;
  constexpr int BPL  = (GU && !EXPERT) ? 8 : 4;     // B planes
  constexpr int NW   = GU ? (EXPERT ? 32 : 64) : 64;// output cols per block (per matrix for GU)
  constexpr int NBF  = BPL/2;                       // B frags per wave
  constexpr int NE   = GU ? ISZ : DIM;              // expert B rows per expert
  constexpr int NT   = KK/32;
  constexpr int NAIT = (APL+3)/4;
  constexpr int NBIT = BPL/4;

  __shared__ uint4 Alds[2][APL*64];
  __shared__ uint4 Blds[2][BPL*64];

  const int tid  = threadIdx.x;
  const int lane = tid & 63, wid = tid >> 6;

  // block mapping: expert -> same-expert adjacent (A-tile sharing);
  //                shared -> same-n adjacent (weight-slice sharing)
  const int bid = blockIdx.x;
  int grp, nblk;
  if constexpr (EXPERT){ grp = bid >> 5; nblk = bid & 31; }
  else                 { grp = bid & 31; nblk = bid >> 5; }
  const int e  = grp;
  const int mb = EXPERT ? grp*CAP : grp*BM;
  const int nb = nblk * NW;

  // ---- A plane pointers (per-lane; gather for expert GU) ----
  const unsigned short* aptr[NAIT];
  #pragma unroll
  for (int i = 0; i < NAIT; ++i){
    int p = wid + i*4; if (p >= APL) p = 0;
    int row = p*16 + (lane & 15);
    int tr;
    if constexpr (EXPERT && GU) tr = stok[mb + row];
    else                        tr = mb + row;
    aptr[i] = Ab + (size_t)tr*KK + (lane >> 4)*8;
  }
  // ---- B plane pointers ----
  const unsigned short* bptr[NBIT];
  #pragma unroll
  for (int i = 0; i < NBIT; ++i){
    int p = wid + i*4;
    int mat = (GU && p >= BPL/2) ? 1 : 0;
    int pc  = GU ? (p & (BPL/2 - 1)) : p;
    const unsigned short* src = mat ? B1 : B0;
    int col = nb + pc*16 + (lane & 15);
    size_t rowg = EXPERT ? ((size_t)e*NE + col) : (size_t)col;
    bptr[i] = src + rowg*KK + (lane >> 4)*8;
  }

  auto stage = [&](int k0, int buf){
    #pragma unroll
    for (int i = 0; i < NAIT; ++i){
      int p = wid + i*4;
      if (i*4 + 3 < APL || p < APL)
        GLOAD16(aptr[i] + k0, (char*)&Alds[buf][0] + p*1024);
    }
    #pragma unroll
    for (int i = 0; i < NBIT; ++i){
      int p = wid + i*4;
      GLOAD16(bptr[i] + k0, (char*)&Blds[buf][0] + p*1024);
    }
  };

  // ---- compute-side plane assignment ----
  const int wn  = wid & 1;
  const int wmp = (wid >> 1) * FM;
  int bpls[NBF];
  if constexpr (GU && !EXPERT){
    bpls[0] = 2*wn; bpls[1] = 2*wn + 1; bpls[2] = 4 + 2*wn; bpls[3] = 5 + 2*wn;
  } else if constexpr (GU){
    bpls[0] = wn; bpls[1] = 2 + wn;
  } else {
    bpls[0] = 2*wn; bpls[1] = 2*wn + 1;
  }

  f32x4 acc[FM][NBF];
  #pragma unroll
  for (int i = 0; i < FM; ++i)
    #pragma unroll
    for (int j = 0; j < NBF; ++j) acc[i][j] = f32x4{0,0,0,0};

  stage(0, 0);
  __syncthreads();

  #pragma unroll 2
  for (int t = 0; t < NT; ++t){
    const int cur = t & 1;
    if (t + 1 < NT) stage((t+1)*32, cur^1);   // prefetch in flight over MFMA
    const char* Al = (const char*)&Alds[cur][0];
    const char* Bl = (const char*)&Blds[cur][0];
    bf16x8 af[FM], bfr[NBF];
    #pragma unroll
    for (int i = 0; i < FM; ++i)
      af[i] = *(const bf16x8*)(Al + (wmp + i)*1024 + lane*16);
    #pragma unroll
    for (int j = 0; j < NBF; ++j)
      bfr[j] = *(const bf16x8*)(Bl + bpls[j]*1024 + lane*16);
    #pragma unroll
    for (int i = 0; i < FM; ++i)
      #pragma unroll
      for (int j = 0; j < NBF; ++j)
        acc[i][j] = __builtin_amdgcn_mfma_f32_16x16x32_bf16(af[i], bfr[j], acc[i][j], 0, 0, 0);
    __syncthreads();
  }

  // ---- epilogue ----
  const int r16 = lane & 15, rg = (lane >> 4) * 4;
  #pragma unroll
  for (int i = 0; i < FM; ++i){
    #pragma unroll
    for (int r = 0; r < 4; ++r){
      const int m = wmp*16 + i*16 + rg + r;
      if constexpr (GU && !EXPERT){
        #pragma unroll
        for (int jj = 0; jj < 2; ++jj){
          float g = acc[i][jj][r], u = acc[i][2+jj][r];
          float h = g / (1.f + __expf(-g)) * u;
          int c = nb + (2*wn + jj)*16 + r16;
          ((unsigned short*)Co)[(size_t)(mb + m)*LDC + c] = (unsigned short)f2bf(h);
        }
      } else if constexpr (GU){
        float g = acc[i][0][r], u = acc[i][1][r];
        float h = g / (1.f + __expf(-g)) * u;
        int c = nb + wn*16 + r16;
        ((unsigned short*)Co)[(size_t)(mb + m)*LDC + c] = (unsigned short)f2bf(h);
      } else if constexpr (EXPERT){
        const int slot = mb + m;
        float w = sw[slot];
        if (w != 0.f){
          int tok = stok[slot];
          #pragma unroll
          for (int j = 0; j < 2; ++j){
            int c = nb + (2*wn + j)*16 + r16;
            atomicAdd(&((float*)Co)[(size_t)tok*LDC + c], w * acc[i][j][r]);
          }
        }
      } else {
        #pragma unroll
        for (int j = 0; j < 2; ++j){
          int c = nb + (2*wn + j)*16 + r16;
          ((float*)Co)[(size_t)(mb + m)*LDC + c] = acc[i][j][r];
        }
      }
    }
  }
}

extern "C" void kernel_launch(void* const* d_in, const int* in_sizes, int n_in,
                              void* d_out, int out_size, void* d_ws, size_t ws_size,
                              hipStream_t stream){
  const float* x  = (const float*)d_in[0];
  const float* rw = (const float*)d_in[1];
  const float* eb = (const float*)d_in[2];
  const float* wg = (const float*)d_in[3];
  const float* wu = (const float*)d_in[4];
  const float* wd = (const float*)d_in[5];
  const float* sg = (const float*)d_in[6];
  const float* su = (const float*)d_in[7];
  const float* sd = (const float*)d_in[8];
  float* out = (float*)d_out;

  // ws layout (~472 MB total)
  char* ws = (char*)d_ws;
  unsigned short* xbf = (unsigned short*)ws; ws += (size_t)T_TOK*DIM*2;
  unsigned short* hsh = (unsigned short*)ws; ws += (size_t)T_TOK*ISH*2;
  unsigned short* hex = (unsigned short*)ws; ws += (size_t)ECAP*ISZ*2;
  unsigned short* sgb = (unsigned short*)ws; ws += (size_t)ISH*DIM*2;
  unsigned short* sub = (unsigned short*)ws; ws += (size_t)ISH*DIM*2;
  unsigned short* sdb = (unsigned short*)ws; ws += (size_t)DIM*ISH*2;
  unsigned short* wgT = (unsigned short*)ws; ws += (size_t)NEXP*ISZ*DIM*2;
  unsigned short* wuT = (unsigned short*)ws; ws += (size_t)NEXP*ISZ*DIM*2;
  unsigned short* wdT = (unsigned short*)ws; ws += (size_t)NEXP*DIM*ISZ*2;
  int*   tki  = (int*)ws;   ws += (size_t)T_TOK*TOPK*4;
  float* tkw  = (float*)ws; ws += (size_t)T_TOK*TOPK*4;
  int*   stok = (int*)ws;   ws += (size_t)ECAP*4;
  float* sw   = (float*)ws; ws += (size_t)ECAP*4;

  // activations -> bf16; router; dispatch
  cvt_k<<<(T_TOK*DIM/8)/256, 256, 0, stream>>>(x, xbf, T_TOK*DIM/8);
  router_k<<<T_TOK/4, 256, 0, stream>>>(x, rw, eb, tki, tkw);
  hipMemsetAsync(stok, 0, (size_t)ECAP*8, stream);   // stok + sw contiguous
  dispatch_k<<<2, 1024, 0, stream>>>(tki, tkw, stok, sw);

  // weights -> bf16 [N,K]
  cvt_k<<<((size_t)ISH*DIM/8)/256, 256, 0, stream>>>(sg, sgb, ISH*DIM/8);
  cvt_k<<<((size_t)ISH*DIM/8)/256, 256, 0, stream>>>(su, sub, ISH*DIM/8);
  cvt_k<<<((size_t)DIM*ISH/8)/256, 256, 0, stream>>>(sd, sdb, DIM*ISH/8);
  tcvt_k<DIM, ISZ><<<dim3(ISZ/128, DIM/128, NEXP), 256, 0, stream>>>(wg, wgT);
  tcvt_k<DIM, ISZ><<<dim3(ISZ/128, DIM/128, NEXP), 256, 0, stream>>>(wu, wuT);
  tcvt_k<ISZ, DIM><<<dim3(DIM/128, ISZ/128, NEXP), 256, 0, stream>>>(wd, wdT);

  // shared MLP: fused gate+up+silu -> hsh ; down -> out (plain store initializes d_out)
  gemm5_k<0,1><<<1024, 256, 0, stream>>>(xbf, sgb, sub, hsh, nullptr, nullptr);
  gemm5_k<0,0><<<1024, 256, 0, stream>>>(hsh, sdb, nullptr, out, nullptr, nullptr);

  // routed experts: fused gate+up+silu -> hex ; down -> atomic scaled scatter into out
  gemm5_k<1,1><<<1024, 256, 0, stream>>>(xbf, wgT, wuT, hex, stok, sw);
  gemm5_k<1,0><<<1024, 256, 0, stream>>>(hex, wdT, nullptr, out, stok, sw);
}